// Round 8
// baseline (477.698 us; speedup 1.0000x reference)
//
#include <hip/hip_runtime.h>

// B=128, C=2048, P=14 (196 px), R=36 boxes.
#define PDIM   14
#define PP     196
#define C_ALL  2048
#define NBOX   36
#define FC_SZ  (128 * 2048)
#define ATT_SZ (128 * 196 * 2048)

// ---------------- K1: att transpose, pixel-tiled ----------------
// block = (b, pixel-group g of 28 px, channel-quarter cq of 512 ch).
// Reads: 112 B contiguous per channel. Writes: per wave 1 KB contiguous,
// per block 28 px x 2 KB strips (4 adjacent blocks complete each 8 KB row).
#define NPX 28
#define KCT 512

__global__ __launch_bounds__(512, 4) void att_kernel(
    const float* __restrict__ images, float* __restrict__ out)
{
    __shared__ float lds[NPX * KCT];   // [px][c], 57,344 B -> 2 blocks/CU
    const int t   = threadIdx.x;
    const int bid = blockIdx.x;
    const int cq  = bid & 3;           // 4 channel quarters
    const int g   = (bid >> 2) % 7;    // 7 pixel groups (7*28 = 196 exact)
    const int b   = bid / 28;
    const int c0  = cq << 9;
    const int p0  = g * NPX;

    // stage: thread t owns channel c0+t; 7 float4 = 112 B contiguous.
    // LDS writes: lanes -> consecutive c words, conflict-free.
    const float* src = images + ((size_t)b * C_ALL + c0 + t) * PP + p0;
    #pragma unroll
    for (int k = 0; k < 7; ++k) {
        float4 v = *(const float4*)(src + (k << 2));
        int px = k << 2;
        lds[(px + 0) * KCT + t] = v.x;
        lds[(px + 1) * KCT + t] = v.y;
        lds[(px + 2) * KCT + t] = v.z;
        lds[(px + 3) * KCT + t] = v.w;
    }
    __syncthreads();

    // store: 28 px x 128 float4 = 3584 tasks, 7/thread. Per wave: fixed px,
    // j4 consecutive -> b128 LDS reads conflict-free, 1 KB contiguous store.
    float* att = out + FC_SZ + ((size_t)b * PP + p0) * C_ALL + c0;
    #pragma unroll
    for (int k = 0; k < 7; ++k) {
        int idx = t + (k << 9);
        int px  = idx >> 7;
        int j4  = (idx & 127) << 2;
        float4 v = *(const float4*)(lds + px * KCT + j4);
        *(float4*)(att + (size_t)px * C_ALL + j4) = v;
    }
}

// ---------------- K2: fc + bu (round-7 kernel, att store removed) ----------
#define CT   32
#define ROW  36

__global__ __launch_bounds__(256, 5) void fcbu_kernel(
    const float* __restrict__ images,
    const float* __restrict__ boxes,
    float* __restrict__ out)
{
    __shared__ float tile[PP * ROW];
    __shared__ float part[4][CT];
    __shared__ int   boxp[NBOX];

    const int t  = threadIdx.x;
    const int b  = blockIdx.x >> 6;
    const int c0 = (blockIdx.x & 63) << 5;

    if (t < NBOX) {
        const float4 bv = *(const float4*)(boxes + ((size_t)b * NBOX + t) * 4);
        int x1 = (int)rintf(bv.x * 14.0f);
        int y1 = (int)rintf(bv.y * 14.0f);
        int x2 = (int)rintf(bv.z * 14.0f);
        int y2 = (int)rintf(bv.w * 14.0f);
        if (x1 == x2) { if (x2 < PDIM) x2++; else if (x1 > 0) x1--; }
        if (y1 == y2) { if (y2 < PDIM) y2++; else if (y1 > 0) y1--; }
        boxp[t] = x1 | (y1 << 8) | (x2 << 16) | (y2 << 24);
    }

    const float4* src =
        (const float4*)(images + (size_t)b * C_ALL * PP + (size_t)c0 * PP);
    #pragma unroll
    for (int k = 0; k < 7; ++k) {
        int tau = t + (k << 8);
        if (tau < CT * 49) {
            int cL   = tau & 15;
            int rest = tau >> 4;
            int j4   = rest % 49;
            int c    = ((rest / 49) << 4) + cL;
            float4 v = src[c * 49 + j4];
            int p0 = j4 << 2;
            tile[(p0 + 0) * ROW + c] = v.x;
            tile[(p0 + 1) * ROW + c] = v.y;
            tile[(p0 + 2) * ROW + c] = v.z;
            tile[(p0 + 3) * ROW + c] = v.w;
        }
    }
    __syncthreads();

    // fc partial sums (same indexing as before, global store dropped)
    float4 acc = {0.f, 0.f, 0.f, 0.f};
    #pragma unroll
    for (int k = 0; k < 7; ++k) {
        int tau = t + (k << 8);
        if (tau < PP * 8) {
            int p = tau >> 3, l = tau & 7;
            float4 v = *(const float4*)(tile + p * ROW + (l << 2));
            acc.x += v.x; acc.y += v.y; acc.z += v.z; acc.w += v.w;
        }
    }
    #pragma unroll
    for (int m = 8; m < 64; m <<= 1) {
        acc.x += __shfl_xor(acc.x, m);
        acc.y += __shfl_xor(acc.y, m);
        acc.z += __shfl_xor(acc.z, m);
        acc.w += __shfl_xor(acc.w, m);
    }
    if ((t & 63) < 8)
        ((float4*)part)[(t >> 6) * 8 + (t & 7)] = acc;
    __syncthreads();
    if (t < CT) {
        float s = part[0][t] + part[1][t] + part[2][t] + part[3][t];
        out[(size_t)b * C_ALL + c0 + t] = s * (1.0f / 196.0f);
    }

    float* bu = out + FC_SZ + ATT_SZ + (size_t)b * NBOX * C_ALL + c0;
    #pragma unroll
    for (int k = 0; k < 5; ++k) {
        int tau = t + (k << 8);
        if (tau < NBOX * CT) {
            int r = tau >> 5, cc = tau & 31;
            int pk = boxp[r];
            int x1 = pk & 255, y1 = (pk >> 8) & 255;
            int x2 = (pk >> 16) & 255, y2 = pk >> 24;
            float s = 0.f;
            for (int i = y1; i < y2; ++i) {
                const float* rowp = tile + (i * PDIM) * ROW + cc;
                for (int j = x1; j < x2; ++j)
                    s += rowp[j * ROW];
            }
            bu[(size_t)r * C_ALL + cc] = s / (float)((y2 - y1) * (x2 - x1));
        }
    }
}

extern "C" void kernel_launch(void* const* d_in, const int* in_sizes, int n_in,
                              void* d_out, int out_size, void* d_ws, size_t ws_size,
                              hipStream_t stream) {
    const float* images = (const float*)d_in[0];
    const float* boxes  = (const float*)d_in[1];
    float* out          = (float*)d_out;
    // K2 first: contiguous input read warms L3 for K1's gather-side reads.
    hipLaunchKernelGGL(fcbu_kernel, dim3(8192), dim3(256), 0, stream,
                       images, boxes, out);
    // K1: 128 b x 7 px-groups x 4 ch-quarters = 3584 blocks, 512 threads.
    hipLaunchKernelGGL(att_kernel, dim3(3584), dim3(512), 0, stream,
                       images, out);
}